// Round 3
// baseline (530.566 us; speedup 1.0000x reference)
//
#include <hip/hip_runtime.h>
#include <hip/hip_bf16.h>

typedef __attribute__((ext_vector_type(8))) short short8;
typedef __attribute__((ext_vector_type(4))) float f32x4;

#define LDS_BYTES 40960

#if __has_builtin(__builtin_amdgcn_cvt_pk_bf16_f32)
typedef __attribute__((ext_vector_type(2))) __bf16 bf16x2;
__device__ __forceinline__ unsigned pk2bf(float a, float b){
  bf16x2 v = __builtin_amdgcn_cvt_pk_bf16_f32(a, b);
  return __builtin_bit_cast(unsigned, v);
}
__device__ __forceinline__ unsigned short f2bf(float x){
  bf16x2 v = __builtin_amdgcn_cvt_pk_bf16_f32(x, x);
  return (unsigned short)(__builtin_bit_cast(unsigned, v) & 0xFFFFu);
}
#else
__device__ __forceinline__ unsigned short f2bf(float x){
  unsigned u = __float_as_uint(x);
  u += 0x7FFFu + ((u >> 16) & 1u);
  return (unsigned short)(u >> 16);
}
__device__ __forceinline__ unsigned pk2bf(float a, float b){
  return (unsigned)f2bf(a) | ((unsigned)f2bf(b) << 16);
}
#endif

__device__ __forceinline__ float bflo(unsigned u){ return __uint_as_float(u << 16); }
__device__ __forceinline__ float bfhi(unsigned u){ return __uint_as_float(u & 0xFFFF0000u); }
__device__ __forceinline__ float bf1(unsigned short h){ return __uint_as_float(((unsigned)h) << 16); }

// ---------------- weight pre-pack: fp32 [K][N] -> bf16 MFMA B-fragments ----------------
// lane reads W[kf*32 + (lane>>4)*8 + j][nt*16 + (lane&15)]
// map: qkv nt*3+kf (54) | out 54+nt*3+kf (18) | ffn1 72+nt*3+kf (36) | ffn2 108+nt*6+kf (36)
__global__ void pack_weights(const float* __restrict__ qkv_w, const float* __restrict__ out_w,
                             const float* __restrict__ ffn_w1, const float* __restrict__ ffn_w2,
                             short8* __restrict__ wsv){
  int f = blockIdx.x, lane = threadIdx.x;
  const float* W; int N, nt, kf;
  if (f < 54)      { W = qkv_w;  N = 288; nt = f/3;        kf = f%3; }
  else if (f < 72) { int i=f-54;  W = out_w;  N = 96;  nt = i/3; kf = i%3; }
  else if (f < 108){ int i=f-72;  W = ffn_w1; N = 192; nt = i/3; kf = i%3; }
  else             { int i=f-108; W = ffn_w2; N = 96;  nt = i/6; kf = i%6; }
  int n = lane & 15, kq = lane >> 4;
  short8 v;
#pragma unroll
  for (int j = 0; j < 8; ++j){
    int k = kf*32 + kq*8 + j;
    v[j] = (short)f2bf(W[(size_t)k * N + nt*16 + n]);
  }
  wsv[f*64 + lane] = v;
}

// ---------------- fused block kernel ----------------
// 512 thr (8 waves); windows 3g..3g+2 = unique tokens 24g..24g+31 (1023 = 3*341)
// LDS 40960 B -> 4 blocks/CU (32 waves/CU) with launch_bounds(512,8)
__global__ __launch_bounds__(512, 8)
void fused_block(const float* __restrict__ x,
                 const float* __restrict__ ln1_g, const float* __restrict__ ln1_b,
                 const float* __restrict__ qkv_b,
                 const float* __restrict__ out_b,
                 const float* __restrict__ ln2_g, const float* __restrict__ ln2_b,
                 const float* __restrict__ ffn_b1, const float* __restrict__ ffn_b2,
                 const float* __restrict__ pln_g, const float* __restrict__ pln_b,
                 const short8* __restrict__ wsv,
                 float* __restrict__ out)
{
  __shared__ __align__(16) char smem[LDS_BYTES];
  unsigned short* hres  = (unsigned short*)smem;          // [48][104] bf16 residual trunk
  unsigned*       hresU = (unsigned*)smem;                // same, u32 view (stride 52)
  unsigned short* Pb    = (unsigned short*)smem;          // overlay (attn phase only): [8][16][24]
  unsigned short* buf1  = (unsigned short*)(smem + 9984); // [48][104]: hln(32r) -> o -> h2
  unsigned*       buf1U = (unsigned*)(smem + 9984);
  unsigned short* buf2  = (unsigned short*)(smem + 19968);// q[32][104]|k[32][104]|vT[96][40] -> f1[48][200]
  unsigned*       buf2U = (unsigned*)(smem + 19968);

  const int tid  = threadIdx.x;
  const int wave = tid >> 6, lane = tid & 63;
  const int lm   = lane & 15, quad = lane >> 4;
  const int g = blockIdx.x, b = blockIdx.y;
  const int t0 = 24 * g;
  const size_t xbase = ((size_t)b * 8192 + t0) * 96;

  const int KOFF = 3328;   // el offset of k in buf2
  const int VOFF = 6656;   // el offset of vT in buf2

  // ---------- LN1 over 32 unique tokens -> hln bf16 (buf1); thread = (row, 6 consecutive cols)
  {
    const int row = tid >> 4, j = tid & 15;
    const float* xr = x + xbase + (size_t)row*96 + 6*j;
    float v[6];
#pragma unroll
    for (int e = 0; e < 3; ++e){ float2 t = *(const float2*)(xr + 2*e); v[2*e]=t.x; v[2*e+1]=t.y; }
    float s = 0.f, q2 = 0.f;
#pragma unroll
    for (int e = 0; e < 6; ++e){ s += v[e]; q2 += v[e]*v[e]; }
#pragma unroll
    for (int m = 1; m < 16; m <<= 1){ s += __shfl_xor(s, m, 16); q2 += __shfl_xor(q2, m, 16); }
    float mean = s * (1.f/96.f);
    float rstd = rsqrtf(q2 * (1.f/96.f) - mean*mean + 1e-5f);
#pragma unroll
    for (int e = 0; e < 3; ++e){
      float2 gg = *(const float2*)(ln1_g + 6*j + 2*e);
      float2 bb = *(const float2*)(ln1_b + 6*j + 2*e);
      buf1U[row*52 + 3*j + e] = pk2bf((v[2*e]-mean)*rstd*gg.x+bb.x,
                                      (v[2*e+1]-mean)*rstd*gg.y+bb.y);
    }
  }
  __syncthreads();

  // ---------- QKV: M=32, N=288 (18 nt), K=96; A-frags hoisted per wave (fixed mt)
  {
    const int mt = wave & 1, p = wave >> 1;
    const unsigned short* arow = buf1 + (16*mt + lm)*104 + quad*8;
    short8 a0 = *(const short8*)(arow);
    short8 a1 = *(const short8*)(arow + 32);
    short8 a2 = *(const short8*)(arow + 64);
    for (int nt = p; nt < 18; nt += 4){
      f32x4 acc = {0.f,0.f,0.f,0.f};
      acc = __builtin_amdgcn_mfma_f32_16x16x32_bf16(a0, wsv[(nt*3+0)*64 + lane], acc, 0, 0, 0);
      acc = __builtin_amdgcn_mfma_f32_16x16x32_bf16(a1, wsv[(nt*3+1)*64 + lane], acc, 0, 0, 0);
      acc = __builtin_amdgcn_mfma_f32_16x16x32_bf16(a2, wsv[(nt*3+2)*64 + lane], acc, 0, 0, 0);
      int col = nt*16 + lm;
      float bias = qkv_b[col];
      if (nt < 6){                          // q [tok][col]
#pragma unroll
        for (int r = 0; r < 4; ++r)
          buf2[(16*mt + quad*4 + r)*104 + col] = f2bf(acc[r] + bias);
      } else if (nt < 12){                  // k [tok][col]
        int cl = col - 96;
#pragma unroll
        for (int r = 0; r < 4; ++r)
          buf2[KOFF + (16*mt + quad*4 + r)*104 + cl] = f2bf(acc[r] + bias);
      } else {                              // vT [d][tok], 4 consecutive toks -> 2 packed writes
        int d2 = col - 192;
        int w0 = (VOFF >> 1) + d2*20 + 8*mt + 2*quad;
        buf2U[w0]     = pk2bf(acc[0] + bias, acc[1] + bias);
        buf2U[w0 + 1] = pk2bf(acc[2] + bias, acc[3] + bias);
      }
    }
  }
  __syncthreads();

  // ---------- attention: 18 units (3 windows x 6 heads), K=16 zero-padded to 32
  for (int u = wave; u < 18; u += 8){
    int w = u / 6, h = u % 6;
    short8 qa = {0,0,0,0,0,0,0,0}, ka = {0,0,0,0,0,0,0,0};
    if (quad < 2){
      qa = *(const short8*)(buf2 +        (8*w + lm)*104 + h*16 + quad*8);
      ka = *(const short8*)(buf2 + KOFF + (8*w + lm)*104 + h*16 + quad*8);
    }
    f32x4 sc = {0.f,0.f,0.f,0.f};
    sc = __builtin_amdgcn_mfma_f32_16x16x32_bf16(qa, ka, sc, 0, 0, 0);
#pragma unroll
    for (int r = 0; r < 4; ++r){
      int row = quad*4 + r;
      float s = (lm <= row) ? sc[r]*0.25f : -1e30f;
      float mx = s;
#pragma unroll
      for (int m = 1; m < 16; m <<= 1) mx = fmaxf(mx, __shfl_xor(mx, m, 16));
      float p = __expf(s - mx);
      float sum = p;
#pragma unroll
      for (int m = 1; m < 16; m <<= 1) sum += __shfl_xor(sum, m, 16);
      Pb[wave*384 + row*24 + lm] = f2bf(p / sum);
    }
    asm volatile("s_waitcnt lgkmcnt(0)" ::: "memory");
    short8 pa = {0,0,0,0,0,0,0,0}, va = {0,0,0,0,0,0,0,0};
    if (quad < 2){
      pa = *(const short8*)(Pb + wave*384 + lm*24 + quad*8);
      va = *(const short8*)(buf2 + VOFF + (h*16 + lm)*40 + 8*w + quad*8);
    }
    f32x4 oc = {0.f,0.f,0.f,0.f};
    oc = __builtin_amdgcn_mfma_f32_16x16x32_bf16(pa, va, oc, 0, 0, 0);
#pragma unroll
    for (int r = 0; r < 4; ++r)
      buf1[(w*16 + quad*4 + r)*104 + h*16 + lm] = f2bf(oc[r]);   // o (hln dead)
  }
  __syncthreads();

  // ---------- out-proj + residual: 18 tiles (3 w x 6 nt), K=96 -> hres bf16 (Pb dead)
  for (int tile = wave; tile < 18; tile += 8){
    int w = tile / 6, nt = tile % 6;
    f32x4 acc = {0.f,0.f,0.f,0.f};
#pragma unroll
    for (int kf = 0; kf < 3; ++kf){
      short8 a = *(const short8*)(buf1 + (w*16 + lm)*104 + kf*32 + quad*8);
      acc = __builtin_amdgcn_mfma_f32_16x16x32_bf16(a, wsv[(54 + nt*3 + kf)*64 + lane], acc, 0, 0, 0);
    }
    int col = nt*16 + lm;
    float bias = out_b[col];
#pragma unroll
    for (int r = 0; r < 4; ++r){
      int i2 = quad*4 + r;
      float seg = x[xbase + (size_t)(8*w + i2)*96 + col];
      hres[(w*16 + i2)*104 + col] = f2bf(acc[r] + bias + seg);
    }
  }
  __syncthreads();

  // ---------- LN2: 48 rows -> h2 bf16 (buf1, o dead); thread = (row, 6 cols)
  {
    const int j = tid & 15;
#pragma unroll
    for (int p = 0; p < 2; ++p){
      int row = p*32 + (tid >> 4);
      if (row < 48){
        float v[6];
#pragma unroll
        for (int e = 0; e < 3; ++e){
          unsigned u = hresU[row*52 + 3*j + e];
          v[2*e] = bflo(u); v[2*e+1] = bfhi(u);
        }
        float s = 0.f, q2 = 0.f;
#pragma unroll
        for (int e = 0; e < 6; ++e){ s += v[e]; q2 += v[e]*v[e]; }
#pragma unroll
        for (int m = 1; m < 16; m <<= 1){ s += __shfl_xor(s, m, 16); q2 += __shfl_xor(q2, m, 16); }
        float mean = s * (1.f/96.f);
        float rstd = rsqrtf(q2 * (1.f/96.f) - mean*mean + 1e-5f);
#pragma unroll
        for (int e = 0; e < 3; ++e){
          float2 gg = *(const float2*)(ln2_g + 6*j + 2*e);
          float2 bb = *(const float2*)(ln2_b + 6*j + 2*e);
          buf1U[row*52 + 3*j + e] = pk2bf((v[2*e]-mean)*rstd*gg.x+bb.x,
                                          (v[2*e+1]-mean)*rstd*gg.y+bb.y);
        }
      }
    }
  }
  __syncthreads();

  // ---------- FFN1 + gelu: 36 tiles (3 mt x 12 nt), K=96 -> f1 bf16 (buf2, stride 200)
  for (int tile = wave; tile < 36; tile += 8){
    int mt = tile % 3, nt = tile / 3;
    f32x4 acc = {0.f,0.f,0.f,0.f};
#pragma unroll
    for (int kf = 0; kf < 3; ++kf){
      short8 a = *(const short8*)(buf1 + (mt*16 + lm)*104 + kf*32 + quad*8);
      acc = __builtin_amdgcn_mfma_f32_16x16x32_bf16(a, wsv[(72 + nt*3 + kf)*64 + lane], acc, 0, 0, 0);
    }
    float bias = ffn_b1[nt*16 + lm];
#pragma unroll
    for (int r = 0; r < 4; ++r){
      float u = acc[r] + bias;
      float z = 0.7978845608f * (u + 0.044715f * u*u*u);
      z = fminf(fmaxf(z, -10.f), 10.f);
      float e2 = __expf(2.f * z);
      float th = (e2 - 1.f) / (e2 + 1.f);
      buf2[(mt*16 + quad*4 + r)*200 + nt*16 + lm] = f2bf(0.5f * u * (1.f + th));
    }
  }
  __syncthreads();

  // ---------- FFN2 + residual: 18 tiles (3 mt x 6 nt), K=192 -> hres bf16 RMW
  for (int tile = wave; tile < 18; tile += 8){
    int mt = tile / 6, nt = tile % 6;
    f32x4 acc = {0.f,0.f,0.f,0.f};
#pragma unroll
    for (int kf = 0; kf < 6; ++kf){
      short8 a = *(const short8*)(buf2 + (mt*16 + lm)*200 + kf*32 + quad*8);
      acc = __builtin_amdgcn_mfma_f32_16x16x32_bf16(a, wsv[(108 + nt*6 + kf)*64 + lane], acc, 0, 0, 0);
    }
    int col = nt*16 + lm;
    float bias = ffn_b2[col];
#pragma unroll
    for (int r = 0; r < 4; ++r){
      int idx = (mt*16 + quad*4 + r)*104 + col;
      hres[idx] = f2bf(bf1(hres[idx]) + acc[r] + bias);
    }
  }
  __syncthreads();

  // ---------- merged post-LN + combine + store (each h-row normalized exactly once)
  {
    const int i = tid >> 4, j = tid & 15;
    const int l = t0 + i;
    const size_t obase = ((size_t)b * 8192 + l) * 96;
    int rowA, rowB = -1;
    if (i < 8)       rowA = i;
    else if (i < 16){ rowA = i;            rowB = 16 + (i - 8); }
    else if (i < 24){ rowA = 16 + (i - 8); rowB = 32 + (i - 16); }
    else             rowA = 32 + (i - 16);

    float g6[6], b6[6];
#pragma unroll
    for (int e = 0; e < 3; ++e){
      float2 gv = *(const float2*)(pln_g + 6*j + 2*e);
      float2 bv = *(const float2*)(pln_b + 6*j + 2*e);
      g6[2*e] = gv.x; g6[2*e+1] = gv.y; b6[2*e] = bv.x; b6[2*e+1] = bv.y;
    }
    float yA[6];
    {
      float v[6];
#pragma unroll
      for (int e = 0; e < 3; ++e){
        unsigned u = hresU[rowA*52 + 3*j + e];
        v[2*e] = bflo(u); v[2*e+1] = bfhi(u);
      }
      float s = 0.f, q2 = 0.f;
#pragma unroll
      for (int e = 0; e < 6; ++e){ s += v[e]; q2 += v[e]*v[e]; }
#pragma unroll
      for (int m = 1; m < 16; m <<= 1){ s += __shfl_xor(s, m, 16); q2 += __shfl_xor(q2, m, 16); }
      float mean = s * (1.f/96.f);
      float rstd = rsqrtf(q2 * (1.f/96.f) - mean*mean + 1e-5f);
#pragma unroll
      for (int e = 0; e < 6; ++e) yA[e] = (v[e]-mean)*rstd*g6[e] + b6[e];
    }
    if (rowB >= 0){
      float yB[6];
      {
        float v[6];
#pragma unroll
        for (int e = 0; e < 3; ++e){
          unsigned u = hresU[rowB*52 + 3*j + e];
          v[2*e] = bflo(u); v[2*e+1] = bfhi(u);
        }
        float s = 0.f, q2 = 0.f;
#pragma unroll
        for (int e = 0; e < 6; ++e){ s += v[e]; q2 += v[e]*v[e]; }
#pragma unroll
        for (int m = 1; m < 16; m <<= 1){ s += __shfl_xor(s, m, 16); q2 += __shfl_xor(q2, m, 16); }
        float mean = s * (1.f/96.f);
        float rstd = rsqrtf(q2 * (1.f/96.f) - mean*mean + 1e-5f);
#pragma unroll
        for (int e = 0; e < 6; ++e) yB[e] = (v[e]-mean)*rstd*g6[e] + b6[e];
      }
#pragma unroll
      for (int e = 0; e < 3; ++e){
        float2 o2;
        o2.x = 0.5f * (yA[2*e]   + yB[2*e]);
        o2.y = 0.5f * (yA[2*e+1] + yB[2*e+1]);
        *(float2*)(out + obase + 6*j + 2*e) = o2;
      }
    } else {
      float inv = (l < 8 || l >= 8184) ? 1.0f : 0.5f;
#pragma unroll
      for (int e = 0; e < 6; ++e)
        atomicAdd(&out[obase + 6*j + e], yA[e] * inv);
    }
  }
}

extern "C" void kernel_launch(void* const* d_in, const int* in_sizes, int n_in,
                              void* d_out, int out_size, void* d_ws, size_t ws_size,
                              hipStream_t stream) {
  const float* x      = (const float*)d_in[0];
  const float* ln1_g  = (const float*)d_in[1];
  const float* ln1_b  = (const float*)d_in[2];
  const float* qkv_w  = (const float*)d_in[3];
  const float* qkv_b  = (const float*)d_in[4];
  const float* out_w  = (const float*)d_in[5];
  const float* out_b  = (const float*)d_in[6];
  const float* ln2_g  = (const float*)d_in[7];
  const float* ln2_b  = (const float*)d_in[8];
  const float* ffn_w1 = (const float*)d_in[9];
  const float* ffn_b1 = (const float*)d_in[10];
  const float* ffn_w2 = (const float*)d_in[11];
  const float* ffn_b2 = (const float*)d_in[12];
  const float* pln_g  = (const float*)d_in[13];
  const float* pln_b  = (const float*)d_in[14];
  float* out = (float*)d_out;
  short8* wsv = (short8*)d_ws;

  hipMemsetAsync(d_out, 0, (size_t)out_size * sizeof(float), stream);
  pack_weights<<<144, 64, 0, stream>>>(qkv_w, out_w, ffn_w1, ffn_w2, wsv);
  fused_block<<<dim3(341, 32), 512, 0, stream>>>(
      x, ln1_g, ln1_b, qkv_b, out_b, ln2_g, ln2_b, ffn_b1, ffn_b2,
      pln_g, pln_b, (const short8*)wsv, out);
}

// Round 4
// 441.883 us; speedup vs baseline: 1.2007x; 1.2007x over previous
//
#include <hip/hip_runtime.h>
#include <hip/hip_bf16.h>

typedef __attribute__((ext_vector_type(8))) short short8;
typedef __attribute__((ext_vector_type(4))) float f32x4;

#define LDS_BYTES 40960

#if __has_builtin(__builtin_amdgcn_cvt_pk_bf16_f32)
typedef __attribute__((ext_vector_type(2))) __bf16 bf16x2;
__device__ __forceinline__ unsigned pk2bf(float a, float b){
  bf16x2 v = __builtin_amdgcn_cvt_pk_bf16_f32(a, b);
  return __builtin_bit_cast(unsigned, v);
}
__device__ __forceinline__ unsigned short f2bf(float x){
  bf16x2 v = __builtin_amdgcn_cvt_pk_bf16_f32(x, x);
  return (unsigned short)(__builtin_bit_cast(unsigned, v) & 0xFFFFu);
}
#else
__device__ __forceinline__ unsigned short f2bf(float x){
  unsigned u = __float_as_uint(x);
  u += 0x7FFFu + ((u >> 16) & 1u);
  return (unsigned short)(u >> 16);
}
__device__ __forceinline__ unsigned pk2bf(float a, float b){
  return (unsigned)f2bf(a) | ((unsigned)f2bf(b) << 16);
}
#endif

__device__ __forceinline__ float bflo(unsigned u){ return __uint_as_float(u << 16); }
__device__ __forceinline__ float bfhi(unsigned u){ return __uint_as_float(u & 0xFFFF0000u); }
__device__ __forceinline__ float bf1(unsigned short h){ return __uint_as_float(((unsigned)h) << 16); }

// ---------------- zero only the atomic-target stripes of out ----------------
// tokens with (l % 24) < 8  (incl. tail 8184..8191 = stripe 341). 33.6 MB vs 100 MB full memset.
__global__ void zero_stripes(float* __restrict__ out){
  int k = blockIdx.x;          // 0..341
  int b = blockIdx.y;          // 0..31
  int t = threadIdx.x;         // 0..191 : 8 tokens x 24 float4
  int tok = 24*k + (t / 24);
  f32x4 z = {0.f, 0.f, 0.f, 0.f};
  *(f32x4*)(out + ((size_t)b*8192 + tok)*96 + 4*(t % 24)) = z;
}

// ---------------- weight pre-pack: fp32 [K][N] -> bf16 MFMA B-fragments ----------------
// lane reads W[kf*32 + (lane>>4)*8 + j][nt*16 + (lane&15)]
// map: qkv nt*3+kf (54) | out 54+nt*3+kf (18) | ffn1 72+nt*3+kf (36) | ffn2 108+nt*6+kf (36)
__global__ void pack_weights(const float* __restrict__ qkv_w, const float* __restrict__ out_w,
                             const float* __restrict__ ffn_w1, const float* __restrict__ ffn_w2,
                             short8* __restrict__ wsv){
  int f = blockIdx.x, lane = threadIdx.x;
  const float* W; int N, nt, kf;
  if (f < 54)      { W = qkv_w;  N = 288; nt = f/3;        kf = f%3; }
  else if (f < 72) { int i=f-54;  W = out_w;  N = 96;  nt = i/3; kf = i%3; }
  else if (f < 108){ int i=f-72;  W = ffn_w1; N = 192; nt = i/3; kf = i%3; }
  else             { int i=f-108; W = ffn_w2; N = 96;  nt = i/6; kf = i%6; }
  int n = lane & 15, kq = lane >> 4;
  short8 v;
#pragma unroll
  for (int j = 0; j < 8; ++j){
    int k = kf*32 + kq*8 + j;
    v[j] = (short)f2bf(W[(size_t)k * N + nt*16 + n]);
  }
  wsv[f*64 + lane] = v;
}

// ---------------- fused block kernel ----------------
// 512 thr (8 waves); windows 3g..3g+2 = unique tokens 24g..24g+31 (1023 = 3*341)
// LDS 40960 B -> 4 blocks/CU (32 waves/CU) with launch_bounds(512,8)
__global__ __launch_bounds__(512, 8)
void fused_block(const float* __restrict__ x,
                 const float* __restrict__ ln1_g, const float* __restrict__ ln1_b,
                 const float* __restrict__ qkv_b,
                 const float* __restrict__ out_b,
                 const float* __restrict__ ln2_g, const float* __restrict__ ln2_b,
                 const float* __restrict__ ffn_b1, const float* __restrict__ ffn_b2,
                 const float* __restrict__ pln_g, const float* __restrict__ pln_b,
                 const short8* __restrict__ wsv,
                 float* __restrict__ out)
{
  __shared__ __align__(16) char smem[LDS_BYTES];
  unsigned short* hres  = (unsigned short*)smem;          // [48][104] bf16 residual trunk
  unsigned*       hresU = (unsigned*)smem;                // same, u32 view (stride 52)
  unsigned short* Pb    = (unsigned short*)smem;          // overlay (attn phase only): [8][16][24]
  unsigned short* buf1  = (unsigned short*)(smem + 9984); // [48][104]: hln(32r) -> o -> h2
  unsigned*       buf1U = (unsigned*)(smem + 9984);
  unsigned short* buf2  = (unsigned short*)(smem + 19968);// q[32][104]|k[32][104]|vT[96][40] -> f1[48][200]
  unsigned*       buf2U = (unsigned*)(smem + 19968);

  const int tid  = threadIdx.x;
  const int wave = tid >> 6, lane = tid & 63;
  const int lm   = lane & 15, quad = lane >> 4;
  const int g = blockIdx.x, b = blockIdx.y;
  const int t0 = 24 * g;
  const size_t xbase = ((size_t)b * 8192 + t0) * 96;

  const int KOFF = 3328;   // el offset of k in buf2
  const int VOFF = 6656;   // el offset of vT in buf2

  // ---------- LN1 over 32 unique tokens -> hln bf16 (buf1); thread = (row, 6 consecutive cols)
  {
    const int row = tid >> 4, j = tid & 15;
    const float* xr = x + xbase + (size_t)row*96 + 6*j;
    float v[6];
#pragma unroll
    for (int e = 0; e < 3; ++e){ float2 t = *(const float2*)(xr + 2*e); v[2*e]=t.x; v[2*e+1]=t.y; }
    float s = 0.f, q2 = 0.f;
#pragma unroll
    for (int e = 0; e < 6; ++e){ s += v[e]; q2 += v[e]*v[e]; }
#pragma unroll
    for (int m = 1; m < 16; m <<= 1){ s += __shfl_xor(s, m, 16); q2 += __shfl_xor(q2, m, 16); }
    float mean = s * (1.f/96.f);
    float rstd = rsqrtf(q2 * (1.f/96.f) - mean*mean + 1e-5f);
#pragma unroll
    for (int e = 0; e < 3; ++e){
      float2 gg = *(const float2*)(ln1_g + 6*j + 2*e);
      float2 bb = *(const float2*)(ln1_b + 6*j + 2*e);
      buf1U[row*52 + 3*j + e] = pk2bf((v[2*e]-mean)*rstd*gg.x+bb.x,
                                      (v[2*e+1]-mean)*rstd*gg.y+bb.y);
    }
  }
  __syncthreads();

  // ---------- QKV: M=32, N=288 (18 nt), K=96; A-frags hoisted per wave (fixed mt)
  {
    const int mt = wave & 1, p = wave >> 1;
    const unsigned short* arow = buf1 + (16*mt + lm)*104 + quad*8;
    short8 a0 = *(const short8*)(arow);
    short8 a1 = *(const short8*)(arow + 32);
    short8 a2 = *(const short8*)(arow + 64);
    for (int nt = p; nt < 18; nt += 4){
      f32x4 acc = {0.f,0.f,0.f,0.f};
      acc = __builtin_amdgcn_mfma_f32_16x16x32_bf16(a0, wsv[(nt*3+0)*64 + lane], acc, 0, 0, 0);
      acc = __builtin_amdgcn_mfma_f32_16x16x32_bf16(a1, wsv[(nt*3+1)*64 + lane], acc, 0, 0, 0);
      acc = __builtin_amdgcn_mfma_f32_16x16x32_bf16(a2, wsv[(nt*3+2)*64 + lane], acc, 0, 0, 0);
      int col = nt*16 + lm;
      float bias = qkv_b[col];
      if (nt < 6){                          // q [tok][col]
#pragma unroll
        for (int r = 0; r < 4; ++r)
          buf2[(16*mt + quad*4 + r)*104 + col] = f2bf(acc[r] + bias);
      } else if (nt < 12){                  // k [tok][col]
        int cl = col - 96;
#pragma unroll
        for (int r = 0; r < 4; ++r)
          buf2[KOFF + (16*mt + quad*4 + r)*104 + cl] = f2bf(acc[r] + bias);
      } else {                              // vT [d][tok], 4 consecutive toks -> 2 packed writes
        int d2 = col - 192;
        int w0 = (VOFF >> 1) + d2*20 + 8*mt + 2*quad;
        buf2U[w0]     = pk2bf(acc[0] + bias, acc[1] + bias);
        buf2U[w0 + 1] = pk2bf(acc[2] + bias, acc[3] + bias);
      }
    }
  }
  __syncthreads();

  // ---------- attention: 18 units (3 windows x 6 heads), K=16 zero-padded to 32
  for (int u = wave; u < 18; u += 8){
    int w = u / 6, h = u % 6;
    short8 qa = {0,0,0,0,0,0,0,0}, ka = {0,0,0,0,0,0,0,0};
    if (quad < 2){
      qa = *(const short8*)(buf2 +        (8*w + lm)*104 + h*16 + quad*8);
      ka = *(const short8*)(buf2 + KOFF + (8*w + lm)*104 + h*16 + quad*8);
    }
    f32x4 sc = {0.f,0.f,0.f,0.f};
    sc = __builtin_amdgcn_mfma_f32_16x16x32_bf16(qa, ka, sc, 0, 0, 0);
#pragma unroll
    for (int r = 0; r < 4; ++r){
      int row = quad*4 + r;
      float s = (lm <= row) ? sc[r]*0.25f : -1e30f;
      float mx = s;
#pragma unroll
      for (int m = 1; m < 16; m <<= 1) mx = fmaxf(mx, __shfl_xor(mx, m, 16));
      float p = __expf(s - mx);
      float sum = p;
#pragma unroll
      for (int m = 1; m < 16; m <<= 1) sum += __shfl_xor(sum, m, 16);
      Pb[wave*384 + row*24 + lm] = f2bf(p / sum);
    }
    asm volatile("s_waitcnt lgkmcnt(0)" ::: "memory");
    short8 pa = {0,0,0,0,0,0,0,0}, va = {0,0,0,0,0,0,0,0};
    if (quad < 2){
      pa = *(const short8*)(Pb + wave*384 + lm*24 + quad*8);
      va = *(const short8*)(buf2 + VOFF + (h*16 + lm)*40 + 8*w + quad*8);
    }
    f32x4 oc = {0.f,0.f,0.f,0.f};
    oc = __builtin_amdgcn_mfma_f32_16x16x32_bf16(pa, va, oc, 0, 0, 0);
#pragma unroll
    for (int r = 0; r < 4; ++r)
      buf1[(w*16 + quad*4 + r)*104 + h*16 + lm] = f2bf(oc[r]);   // o (hln dead)
  }
  __syncthreads();

  // ---------- out-proj + residual: 18 tiles (3 w x 6 nt), K=96 -> hres bf16 (Pb dead)
  for (int tile = wave; tile < 18; tile += 8){
    int w = tile / 6, nt = tile % 6;
    f32x4 acc = {0.f,0.f,0.f,0.f};
#pragma unroll
    for (int kf = 0; kf < 3; ++kf){
      short8 a = *(const short8*)(buf1 + (w*16 + lm)*104 + kf*32 + quad*8);
      acc = __builtin_amdgcn_mfma_f32_16x16x32_bf16(a, wsv[(54 + nt*3 + kf)*64 + lane], acc, 0, 0, 0);
    }
    int col = nt*16 + lm;
    float bias = out_b[col];
#pragma unroll
    for (int r = 0; r < 4; ++r){
      int i2 = quad*4 + r;
      float seg = x[xbase + (size_t)(8*w + i2)*96 + col];
      hres[(w*16 + i2)*104 + col] = f2bf(acc[r] + bias + seg);
    }
  }
  __syncthreads();

  // ---------- LN2: 48 rows -> h2 bf16 (buf1, o dead); thread = (row, 6 cols)
  {
    const int j = tid & 15;
#pragma unroll
    for (int p = 0; p < 2; ++p){
      int row = p*32 + (tid >> 4);
      if (row < 48){
        float v[6];
#pragma unroll
        for (int e = 0; e < 3; ++e){
          unsigned u = hresU[row*52 + 3*j + e];
          v[2*e] = bflo(u); v[2*e+1] = bfhi(u);
        }
        float s = 0.f, q2 = 0.f;
#pragma unroll
        for (int e = 0; e < 6; ++e){ s += v[e]; q2 += v[e]*v[e]; }
#pragma unroll
        for (int m = 1; m < 16; m <<= 1){ s += __shfl_xor(s, m, 16); q2 += __shfl_xor(q2, m, 16); }
        float mean = s * (1.f/96.f);
        float rstd = rsqrtf(q2 * (1.f/96.f) - mean*mean + 1e-5f);
#pragma unroll
        for (int e = 0; e < 3; ++e){
          float2 gg = *(const float2*)(ln2_g + 6*j + 2*e);
          float2 bb = *(const float2*)(ln2_b + 6*j + 2*e);
          buf1U[row*52 + 3*j + e] = pk2bf((v[2*e]-mean)*rstd*gg.x+bb.x,
                                          (v[2*e+1]-mean)*rstd*gg.y+bb.y);
        }
      }
    }
  }
  __syncthreads();

  // ---------- FFN1 + gelu: 36 tiles (3 mt x 12 nt), K=96 -> f1 bf16 (buf2, stride 200)
  for (int tile = wave; tile < 36; tile += 8){
    int mt = tile % 3, nt = tile / 3;
    f32x4 acc = {0.f,0.f,0.f,0.f};
#pragma unroll
    for (int kf = 0; kf < 3; ++kf){
      short8 a = *(const short8*)(buf1 + (mt*16 + lm)*104 + kf*32 + quad*8);
      acc = __builtin_amdgcn_mfma_f32_16x16x32_bf16(a, wsv[(72 + nt*3 + kf)*64 + lane], acc, 0, 0, 0);
    }
    float bias = ffn_b1[nt*16 + lm];
#pragma unroll
    for (int r = 0; r < 4; ++r){
      float u = acc[r] + bias;
      float z = 0.7978845608f * (u + 0.044715f * u*u*u);
      z = fminf(fmaxf(z, -10.f), 10.f);
      float e2 = __expf(2.f * z);
      float th = (e2 - 1.f) / (e2 + 1.f);
      buf2[(mt*16 + quad*4 + r)*200 + nt*16 + lm] = f2bf(0.5f * u * (1.f + th));
    }
  }
  __syncthreads();

  // ---------- FFN2 + residual: 18 tiles (3 mt x 6 nt), K=192 -> hres bf16 RMW
  for (int tile = wave; tile < 18; tile += 8){
    int mt = tile / 6, nt = tile % 6;
    f32x4 acc = {0.f,0.f,0.f,0.f};
#pragma unroll
    for (int kf = 0; kf < 6; ++kf){
      short8 a = *(const short8*)(buf2 + (mt*16 + lm)*200 + kf*32 + quad*8);
      acc = __builtin_amdgcn_mfma_f32_16x16x32_bf16(a, wsv[(108 + nt*6 + kf)*64 + lane], acc, 0, 0, 0);
    }
    int col = nt*16 + lm;
    float bias = ffn_b2[col];
#pragma unroll
    for (int r = 0; r < 4; ++r){
      int idx = (mt*16 + quad*4 + r)*104 + col;
      hres[idx] = f2bf(bf1(hres[idx]) + acc[r] + bias);
    }
  }
  __syncthreads();

  // ---------- merged post-LN + combine + store; thread = (token i, c0), cols c0+16e
  // per-instruction contiguity: lanes 0..15 cover 64 contiguous bytes per store/atomic
  {
    const int i = tid >> 4, c0 = tid & 15;
    const int l = t0 + i;
    const size_t obase = ((size_t)b * 8192 + l) * 96;
    int rowA, rowB = -1;
    if (i < 8)       rowA = i;
    else if (i < 16){ rowA = i;            rowB = 16 + (i - 8); }
    else if (i < 24){ rowA = 16 + (i - 8); rowB = 32 + (i - 16); }
    else             rowA = 32 + (i - 16);

    float g6[6], b6[6];
#pragma unroll
    for (int e = 0; e < 6; ++e){ g6[e] = pln_g[c0 + 16*e]; b6[e] = pln_b[c0 + 16*e]; }

    float yA[6];
    {
      float v[6];
#pragma unroll
      for (int e = 0; e < 6; ++e) v[e] = bf1(hres[rowA*104 + c0 + 16*e]);
      float s = 0.f, q2 = 0.f;
#pragma unroll
      for (int e = 0; e < 6; ++e){ s += v[e]; q2 += v[e]*v[e]; }
#pragma unroll
      for (int m = 1; m < 16; m <<= 1){ s += __shfl_xor(s, m, 16); q2 += __shfl_xor(q2, m, 16); }
      float mean = s * (1.f/96.f);
      float rstd = rsqrtf(q2 * (1.f/96.f) - mean*mean + 1e-5f);
#pragma unroll
      for (int e = 0; e < 6; ++e) yA[e] = (v[e]-mean)*rstd*g6[e] + b6[e];
    }
    if (rowB >= 0){
      float yB[6];
      {
        float v[6];
#pragma unroll
        for (int e = 0; e < 6; ++e) v[e] = bf1(hres[rowB*104 + c0 + 16*e]);
        float s = 0.f, q2 = 0.f;
#pragma unroll
        for (int e = 0; e < 6; ++e){ s += v[e]; q2 += v[e]*v[e]; }
#pragma unroll
        for (int m = 1; m < 16; m <<= 1){ s += __shfl_xor(s, m, 16); q2 += __shfl_xor(q2, m, 16); }
        float mean = s * (1.f/96.f);
        float rstd = rsqrtf(q2 * (1.f/96.f) - mean*mean + 1e-5f);
#pragma unroll
        for (int e = 0; e < 6; ++e) yB[e] = (v[e]-mean)*rstd*g6[e] + b6[e];
      }
#pragma unroll
      for (int e = 0; e < 6; ++e)
        out[obase + c0 + 16*e] = 0.5f * (yA[e] + yB[e]);
    } else {
      float inv = (l < 8 || l >= 8184) ? 1.0f : 0.5f;
#pragma unroll
      for (int e = 0; e < 6; ++e)
        atomicAdd(&out[obase + c0 + 16*e], yA[e] * inv);
    }
  }
}

extern "C" void kernel_launch(void* const* d_in, const int* in_sizes, int n_in,
                              void* d_out, int out_size, void* d_ws, size_t ws_size,
                              hipStream_t stream) {
  const float* x      = (const float*)d_in[0];
  const float* ln1_g  = (const float*)d_in[1];
  const float* ln1_b  = (const float*)d_in[2];
  const float* qkv_w  = (const float*)d_in[3];
  const float* qkv_b  = (const float*)d_in[4];
  const float* out_w  = (const float*)d_in[5];
  const float* out_b  = (const float*)d_in[6];
  const float* ln2_g  = (const float*)d_in[7];
  const float* ln2_b  = (const float*)d_in[8];
  const float* ffn_w1 = (const float*)d_in[9];
  const float* ffn_b1 = (const float*)d_in[10];
  const float* ffn_w2 = (const float*)d_in[11];
  const float* ffn_b2 = (const float*)d_in[12];
  const float* pln_g  = (const float*)d_in[13];
  const float* pln_b  = (const float*)d_in[14];
  float* out = (float*)d_out;
  short8* wsv = (short8*)d_ws;

  zero_stripes<<<dim3(342, 32), 192, 0, stream>>>(out);
  pack_weights<<<144, 64, 0, stream>>>(qkv_w, out_w, ffn_w1, ffn_w2, wsv);
  fused_block<<<dim3(341, 32), 512, 0, stream>>>(
      x, ln1_g, ln1_b, qkv_b, out_b, ln2_g, ln2_b, ffn_b1, ffn_b2,
      pln_g, pln_b, (const short8*)wsv, out);
}